// Round 3
// baseline (1131.248 us; speedup 1.0000x reference)
//
#include <hip/hip_runtime.h>
#include <hip/hip_bf16.h>

#define B_ 8
#define S_ 128
#define H_ 512
#define E_ 512
#define NST 8
#define R_ 1024
#define N2 2048
#define KD 512
#define LDA 72          // LDS row pitch in shorts (fragment ds_read_b128: 2-way = free)
#define NBLK 512        // chain grid: 2 blocks/CU x 256 CUs, co-resident by construction

typedef __hip_bfloat16 bf16;
typedef __attribute__((ext_vector_type(8))) short v8s;
typedef __attribute__((ext_vector_type(4))) float v4f;

__device__ __forceinline__ float sigm(float x){ return 1.0f/(1.0f + expf(-x)); }
__device__ __forceinline__ float load_in(const void* p, long long i, int isb){
    return isb ? __bfloat162float(((const bf16*)p)[i]) : ((const float*)p)[i];
}
__device__ __forceinline__ int idx_read(const int* p, int j, int is64){
    return is64 ? p[2*j] : p[j];
}
__device__ __forceinline__ unsigned short f2b(float v){
    bf16 b = __float2bfloat16(v);
    return *(unsigned short*)&b;
}

// Hand-rolled grid barrier (graph-capturable; no cooperative launch needed).
// Monotonic counter: target = NBLK * phase#. Agent-scope fences give cross-XCD
// visibility (L2 wb + L1 inv on gfx950). One atomic per block per barrier.
__device__ __forceinline__ void gsync(int* bar, int target){
    __syncthreads();
    if (threadIdx.x == 0){
        __threadfence();   // release: make this block's stores visible device-wide
        __hip_atomic_fetch_add(bar, 1, __ATOMIC_RELAXED, __HIP_MEMORY_SCOPE_AGENT);
        while (__hip_atomic_load(bar, __ATOMIC_RELAXED, __HIP_MEMORY_SCOPE_AGENT) < target)
            __builtin_amdgcn_s_sleep(2);
        __threadfence();   // acquire: invalidate stale cached lines
    }
    __syncthreads();
}

// ---- K1: dtype probes (bid 0..14 float tensors, 15/16 int tensors) ----
__global__ void probe_all(const void* t0, const void* t1, const void* t2, const void* t3,
                          const void* t4, const void* t5, const void* t6, const void* t7,
                          const void* t8, const void* t9, const void* t10, const void* t11,
                          const void* t12, const void* t13, const void* t14,
                          const int* __restrict__ ids, const int* __restrict__ tree,
                          int* __restrict__ flags){
    const void* ts[15] = {t0,t1,t2,t3,t4,t5,t6,t7,t8,t9,t10,t11,t12,t13,t14};
    int bid = blockIdx.x, t = threadIdx.x;   // 1024 threads
    int bad = 0;
    if (bid < 15){
        if (t < 512){
            unsigned short u = ((const unsigned short*)ts[bid])[t];
            bad = (((u >> 7) & 0xFF) >= 140);
        }
    } else {
        const int* p = (bid == 15) ? ids : tree;
        int n = (bid == 15) ? 1024 : 2048;
        for (int j = t; j < n; j += 1024)
            if (j & 1) bad |= (p[j] != 0);
    }
    unsigned long long bl = __ballot(bad);
    __shared__ int acc[16];
    if ((t & 63) == 0) acc[t >> 6] = (bl != 0ull) ? 1 : 0;
    __syncthreads();
    if (t == 0){
        int any = 0;
        for (int w = 0; w < 16; ++w) any |= acc[w];
        flags[(bid < 15) ? bid : (16 + bid - 15)] = any ? 0 : 1;
    }
}

// ---- K2: rank+CSR-count (bid<8) + all one-time packs + zero-init (512 thr) ----
#define NB2 320
#define GS2 (NB2*512)
__global__ __launch_bounds__(512)
void rank_pack(const void* __restrict__ Wioux, const void* __restrict__ Wfx,
               const void* __restrict__ Wr, const void* __restrict__ Wl,
               const void* __restrict__ W0, const void* __restrict__ W1,
               const void* __restrict__ W2, const void* __restrict__ W3,
               const void* __restrict__ br, const void* __restrict__ bl,
               const void* __restrict__ b0, const void* __restrict__ b1,
               const void* __restrict__ b2, const void* __restrict__ b3,
               const int* __restrict__ ids, const void* __restrict__ emb,
               const int* __restrict__ tree,
               unsigned short* __restrict__ WxT, unsigned short* __restrict__ WcatT,
               float* __restrict__ bcat, unsigned short* __restrict__ xb,
               float* __restrict__ h0,
               int* __restrict__ msk, int* __restrict__ rnk, int* __restrict__ cnt,
               const int* __restrict__ flags, int* __restrict__ bar){
    int bid = blockIdx.x, tid = threadIdx.x;
    int is64 = flags[17];
    if (bid == 0 && tid == 0) *bar = 0;    // reset chain barrier (replay-safe)
    if (bid < 8){
        int st = bid;
        for (int c = tid; c < R_; c += 512){
            cnt[(0*NST + st)*R_ + c] = 0;
            cnt[(1*NST + st)*R_ + c] = 0;
            cnt[(2*NST + st)*R_ + c] = 0;
        }
        __syncthreads();
        __shared__ int wt[8];
        int runbase = 0;
        for (int ch = 0; ch < 2; ++ch){
            int t = ch*512 + tid;
            int b = t >> 7, s = t & 127;
            int base = (b*NST + st)*3*S_;
            int d0 = idx_read(tree, base + s, is64);
            int rd = (b<<7) + d0;
            int rr = (b<<7) + idx_read(tree, base + S_ + s, is64);
            int rl = (b<<7) + idx_read(tree, base + 2*S_ + s, is64);
            int m = (d0 != 0) ? 1 : 0;
            unsigned long long bal = __ballot(m);
            int lane = tid & 63, wv = tid >> 6;
            if (lane == 0) wt[wv] = __popcll(bal);
            __syncthreads();
            int bp = runbase, tot = 0;
            for (int w = 0; w < wv; ++w) bp += wt[w];
            for (int w = 0; w < 8; ++w) tot += wt[w];
            int rank = bp + __popcll(bal & ((1ull << lane) - 1ull));
            msk[st*R_ + t] = m;
            rnk[st*R_ + t] = m ? rank : 0;
            atomicAdd(&cnt[(0*NST + st)*R_ + rr], 1);
            atomicAdd(&cnt[(1*NST + st)*R_ + rl], 1);
            atomicAdd(&cnt[(2*NST + st)*R_ + rd], 1);
            runbase += tot;
            __syncthreads();
        }
    }
    int gt = bid*512 + tid;
    {   // WxT: 2048 n x 64 k-groups
        int f_wx = flags[1], f_wf = flags[6];
        for (int u = gt; u < 131072; u += GS2){
            int n = u >> 6, k0 = (u & 63)*8;
            unsigned short tmp[8];
            #pragma unroll
            for (int i = 0; i < 8; ++i){
                float v = (n < 1536) ? load_in(Wioux, (long long)(k0+i)*1536 + n, f_wx)
                                     : load_in(Wfx,   (long long)(k0+i)*512 + (n-1536), f_wf);
                tmp[i] = f2b(v);
            }
            *(v8s*)&WxT[(size_t)n*KD + k0] = *(v8s*)tmp;
        }
    }
    {   // WcatT
        int fWr=flags[2], fWl=flags[4], fW0=flags[7], fW1=flags[9], fW2=flags[11], fW3=flags[13];
        for (int u = gt; u < 131072; u += GS2){
            int n = u >> 6, k0 = (u & 63)*8;
            unsigned short tmp[8];
            #pragma unroll
            for (int i = 0; i < 8; ++i){
                long long k = k0 + i;
                float v;
                if      (n <  512) v = load_in(Wr, k*1536 + n, fWr);
                else if (n < 1024) v = load_in(Wl, k*1536 + (n-512), fWl);
                else if (n < 1536) { int c = n-1024; v = load_in(W0, k*512+c, fW0) + load_in(W1, k*512+c, fW1); }
                else               { int c = n-1536; v = load_in(W2, k*512+c, fW2) + load_in(W3, k*512+c, fW3); }
                tmp[i] = f2b(v);
            }
            *(v8s*)&WcatT[(size_t)n*KD + k0] = *(v8s*)tmp;
        }
    }
    {   // bcat
        int fbr=flags[3], fbl=flags[5], fb0=flags[8], fb1=flags[10], fb2=flags[12], fb3=flags[14];
        for (int n = gt; n < 2048; n += GS2){
            float v;
            if      (n <  512) v = load_in(br, n, fbr);
            else if (n < 1024) v = load_in(bl, n-512, fbl);
            else if (n < 1536) v = load_in(b0, n-1024, fb0) + load_in(b1, n-1024, fb1);
            else               v = load_in(b2, n-1536, fb2) + load_in(b3, n-1536, fb3);
            bcat[n] = v;
        }
    }
    {   // xb: 1024 rows x 64 groups
        int f_emb = flags[0], i64i = flags[16];
        for (int u = gt; u < 65536; u += GS2){
            int r = u >> 6, c0 = (u & 63)*8;
            long long base = (long long)idx_read(ids, r, i64i)*E_ + c0;
            unsigned short tmp[8];
            #pragma unroll
            for (int i = 0; i < 8; ++i) tmp[i] = f2b(load_in(emb, base + i, f_emb));
            *(v8s*)&xb[(size_t)r*KD + c0] = *(v8s*)tmp;
        }
    }
    for (int u = gt; u < 262144; u += GS2)   // zero h0+c0 (contiguous 4 MB)
        ((float4*)h0)[u] = make_float4(0.f,0.f,0.f,0.f);
}

// ---- K3: CSR scans ----
__global__ void csr_scan(const int* __restrict__ cnt, int* __restrict__ off,
                         int* __restrict__ cur){
    int st = blockIdx.x, a = blockIdx.y;
    int t = threadIdx.x;   // 1024
    int base = (a*NST + st)*R_;
    __shared__ int sh[R_];
    int v = cnt[base + t];
    sh[t] = v;
    __syncthreads();
    for (int d = 1; d < R_; d <<= 1){
        int x = (t >= d) ? sh[t - d] : 0;
        __syncthreads();
        sh[t] += x;
        __syncthreads();
    }
    int excl = sh[t] - v;
    off[base + t] = excl;
    cur[base + t] = excl;
}

// ---- K4: CSR fill ----
__global__ __launch_bounds__(512)
void csr_fill(const int* __restrict__ tree, int* __restrict__ cur,
              int* __restrict__ ent, const int* __restrict__ flags){
    int is64 = flags[17];
    int st = blockIdx.x;
    for (int ch = 0; ch < 2; ++ch){
        int t = ch*512 + threadIdx.x;
        int b = t >> 7, s = t & 127;
        int base = (b*NST + st)*3*S_;
        int rd = (b<<7) + idx_read(tree, base + s, is64);
        int rr = (b<<7) + idx_read(tree, base + S_ + s, is64);
        int rl = (b<<7) + idx_read(tree, base + 2*S_ + s, is64);
        int p0 = atomicAdd(&cur[(0*NST + st)*R_ + rr], 1);
        ent[(0*NST + st)*R_ + p0] = t;
        int p1 = atomicAdd(&cur[(1*NST + st)*R_ + rl], 1);
        ent[(1*NST + st)*R_ + p1] = t;
        int p2 = atomicAdd(&cur[(2*NST + st)*R_ + rd], 1);
        ent[(2*NST + st)*R_ + p2] = t | (rr << 10) | (rl << 20);
    }
}

// ---- GEMM phase (r7-proven tile code): C[1024][2048] = A@BT^T (+bias) ----
// 64x64 tile, 512 blocks (2/CU), 4 waves 2x2 of 32x32, register-prefetched staging.
// XCD-aware tile map: each XCD (bid&7) owns 4 contiguous bn panels -> B-panel L2 locality.
__device__ __forceinline__ void gemm_phase(const unsigned short* __restrict__ A,
               const unsigned short* __restrict__ BT,
               const float* __restrict__ bias,
               float* __restrict__ C,
               short* __restrict__ As, short* __restrict__ Bs)
{
    int bid = blockIdx.x;
    int bn = (bid & 7)*4 + ((bid >> 3) & 3);   // 0..31, 4 panels per XCD
    int bm = bid >> 5;                          // 0..15
    int tid = threadIdx.x;
    int lane = tid & 63, wave = tid >> 6;
    int wm = wave & 1, wn = wave >> 1;
    int lm = lane & 15, quad = lane >> 4;
    v4f acc[2][2];
    #pragma unroll
    for (int i=0;i<2;++i)
        #pragma unroll
        for (int j=0;j<2;++j) acc[i][j] = (v4f)0.0f;

    int srow = tid >> 3, sg = (tid & 7)*8;
    const unsigned short* Ab = A  + (size_t)(bm*64)*KD;
    const unsigned short* Bb = BT + (size_t)(bn*64)*KD;
    v8s pa[2], pb[2];
    #pragma unroll
    for (int j=0;j<2;++j){
        pa[j] = *(const v8s*)(Ab + (size_t)(j*32+srow)*KD + sg);
        pb[j] = *(const v8s*)(Bb + (size_t)(j*32+srow)*KD + sg);
    }
    for (int k0 = 0; k0 < KD; k0 += 64){
        #pragma unroll
        for (int j=0;j<2;++j){
            *(v8s*)&As[(j*32+srow)*LDA + sg] = pa[j];
            *(v8s*)&Bs[(j*32+srow)*LDA + sg] = pb[j];
        }
        __syncthreads();
        int k1 = k0 + 64;
        if (k1 < KD){
            #pragma unroll
            for (int j=0;j<2;++j){
                pa[j] = *(const v8s*)(Ab + (size_t)(j*32+srow)*KD + k1 + sg);
                pb[j] = *(const v8s*)(Bb + (size_t)(j*32+srow)*KD + k1 + sg);
            }
        }
        #pragma unroll
        for (int kk = 0; kk < 64; kk += 32){
            v8s af[2], bf[2];
            #pragma unroll
            for (int i=0;i<2;++i){
                af[i] = *(const v8s*)&As[(wm*32 + i*16 + lm)*LDA + kk + quad*8];
                bf[i] = *(const v8s*)&Bs[(wn*32 + i*16 + lm)*LDA + kk + quad*8];
            }
            #pragma unroll
            for (int i=0;i<2;++i)
                #pragma unroll
                for (int j=0;j<2;++j)
                    acc[i][j] = __builtin_amdgcn_mfma_f32_16x16x32_bf16(af[i], bf[j], acc[i][j], 0, 0, 0);
        }
        __syncthreads();
    }
    #pragma unroll
    for (int j=0;j<2;++j){
        int n = bn*64 + wn*32 + j*16 + lm;
        float bv = bias ? bias[n] : 0.0f;
        #pragma unroll
        for (int i=0;i<2;++i){
            int m0 = bm*64 + wm*32 + i*16 + quad*4;
            #pragma unroll
            for (int rg = 0; rg < 4; ++rg)
                C[(size_t)(m0+rg)*N2 + n] = acc[i][j][rg] + bv;
        }
    }
}

// ---- epi phase: CSR-gathered scatters + gates + masked-scatter ----
// Re-gridded for 512 blocks x 256 threads: 2 rows/block, 2 cols/thread.
// tstr=0 with T=bcat implements the step-0 (h=0 => T = bias broadcast) shortcut.
__device__ __forceinline__ void epi_phase(const float* __restrict__ XO,
              const float* __restrict__ T, int tstr,
              const float* __restrict__ hc, const float* __restrict__ cc,
              float* __restrict__ hn, float* __restrict__ cn,
              unsigned short* __restrict__ hb, float* __restrict__ out,
              const int* __restrict__ msk, const int* __restrict__ rnk,
              const int* __restrict__ cnt, const int* __restrict__ off,
              const int* __restrict__ ent, int st, int last)
{
    int tid = threadIdx.x;
    int c0 = tid, c1 = tid + 256;
    #pragma unroll
    for (int rr2 = 0; rr2 < 2; ++rr2){
        int r = blockIdx.x*2 + rr2;
        if (!msk[st*R_ + r]){
            float hv0 = hc[(size_t)r*H_ + c0];
            float hv1 = hc[(size_t)r*H_ + c1];
            if (last){
                out[(size_t)r*H_ + c0] = hv0;
                out[(size_t)r*H_ + c1] = hv1;
            } else {
                hn[(size_t)r*H_ + c0] = hv0;
                hn[(size_t)r*H_ + c1] = hv1;
                cn[(size_t)r*H_ + c0] = cc[(size_t)r*H_ + c0];
                cn[(size_t)r*H_ + c1] = cc[(size_t)r*H_ + c1];
                hb[(size_t)r*KD + c0] = f2b(hv0);
                hb[(size_t)r*KD + c1] = f2b(hv1);
            }
            continue;
        }
        int j = rnk[st*R_ + r];
        int bR = off[(0*NST+st)*R_ + j], dR = cnt[(0*NST+st)*R_ + j];
        int bL = off[(1*NST+st)*R_ + j], dL = cnt[(1*NST+st)*R_ + j];
        int bD = off[(2*NST+st)*R_ + j], dD = cnt[(2*NST+st)*R_ + j];
        const int* eR = ent + (0*NST+st)*R_ + bR;
        const int* eL = ent + (1*NST+st)*R_ + bL;
        const int* eD = ent + (2*NST+st)*R_ + bD;
        const float* xo = XO + (size_t)j*N2;
        float scv0 = 0.f, scv1 = 0.f;
        for (int e = 0; e < dR; ++e){
            size_t b = (size_t)eR[e]*tstr;
            scv0 += T[b + c0]; scv1 += T[b + c1];
        }
        for (int e = 0; e < dL; ++e){
            size_t b = (size_t)eL[e]*tstr + 512;
            scv0 += T[b + c0]; scv1 += T[b + c1];
        }
        float fx0 = xo[1536 + c0], fx1 = xo[1536 + c1];
        float csc0 = 0.f, csc1 = 0.f;
        for (int e = 0; e < dD; ++e){
            int pk = eD[e];
            int s  = pk & 1023, ra = (pk >> 10) & 1023, rb = (pk >> 20) & 1023;
            size_t ba = (size_t)ra*tstr + 1024, bb = (size_t)rb*tstr + 1536;
            float f0 = sigm(fx0 + T[ba + c0] + T[bb + c0]);
            float f1 = sigm(fx1 + T[ba + c1] + T[bb + c1]);
            csc0 += f0 * cc[(size_t)s*H_ + c0];
            csc1 += f1 * cc[(size_t)s*H_ + c1];
        }
        float ig0 = sigm(xo[c0] + scv0), ig1 = sigm(xo[c1] + scv1);
        float og0 = sigm(xo[512 + c0]), og1 = sigm(xo[512 + c1]);
        float ug0 = tanhf(xo[1024 + c0]), ug1 = tanhf(xo[1024 + c1]);
        float cf0 = ig0*ug0 + csc0, cf1 = ig1*ug1 + csc1;
        float hf0 = og0 * tanhf(cf0), hf1 = og1 * tanhf(cf1);
        if (last){
            out[(size_t)r*H_ + c0] = hf0;
            out[(size_t)r*H_ + c1] = hf1;
        } else {
            hn[(size_t)r*H_ + c0] = hf0; hn[(size_t)r*H_ + c1] = hf1;
            cn[(size_t)r*H_ + c0] = cf0; cn[(size_t)r*H_ + c1] = cf1;
            hb[(size_t)r*KD + c0] = f2b(hf0); hb[(size_t)r*KD + c1] = f2b(hf1);
        }
    }
}

// ---- fused chain: XO GEMM + epi0 + 7x(GEMM, epi); regular launch + manual grid barrier ----
__global__ __launch_bounds__(256, 2)
void chain_all(const unsigned short* __restrict__ xb,
               const unsigned short* __restrict__ WxT,
               const unsigned short* __restrict__ WcatT,
               const float* __restrict__ bcat,
               float* __restrict__ XO, float* __restrict__ T,
               float* __restrict__ h0, float* __restrict__ c0,
               float* __restrict__ h1, float* __restrict__ c1,
               unsigned short* __restrict__ hb, float* __restrict__ out,
               const int* __restrict__ msk, const int* __restrict__ rnk,
               const int* __restrict__ cnt, const int* __restrict__ off,
               const int* __restrict__ ent, int* bar)
{
    __shared__ short As[64*LDA];
    __shared__ short Bs[64*LDA];
    int gen = 0;

    // phase 0: XO = xb @ WxT^T (no bias)
    gemm_phase(xb, WxT, (const float*)nullptr, XO, As, Bs);
    gsync(bar, NBLK*(++gen));
    // step 0: h==0 -> T is the bias broadcast; no GEMM needed (tstr=0, T=bcat)
    epi_phase(XO, bcat, 0, h0, c0, h1, c1, hb, out, msk, rnk, cnt, off, ent, 0, 0);
    gsync(bar, NBLK*(++gen));

    for (int st = 1; st < NST; ++st){
        const float* hcp = (st & 1) ? h1 : h0;
        const float* ccp = (st & 1) ? c1 : c0;
        float* hnp = (st & 1) ? h0 : h1;
        float* cnp = (st & 1) ? c0 : c1;
        gemm_phase(hb, WcatT, bcat, T, As, Bs);
        gsync(bar, NBLK*(++gen));
        epi_phase(XO, T, N2, hcp, ccp, hnp, cnp, hb, out,
                  msk, rnk, cnt, off, ent, st, (st == NST-1) ? 1 : 0);
        if (st < NST-1) gsync(bar, NBLK*(++gen));
    }
}

extern "C" void kernel_launch(void* const* d_in, const int* in_sizes, int n_in,
                              void* d_out, int out_size, void* d_ws, size_t ws_size,
                              hipStream_t stream) {
    const int* input_ids = (const int*)d_in[0];
    const int* tree      = (const int*)d_in[1];

    char* wp = (char*)d_ws;
    auto alloc = [&](size_t bytes) -> void* {
        void* q = (void*)wp;
        wp += (bytes + 255) & ~(size_t)255;
        return q;
    };
    float*          XO     = (float*)alloc((size_t)R_*N2*4);
    float*          T      = (float*)alloc((size_t)R_*N2*4);
    float*          h0     = (float*)alloc((size_t)R_*H_*4);   // contiguous with c0
    float*          c0     = (float*)alloc((size_t)R_*H_*4);
    float*          h1     = (float*)alloc((size_t)R_*H_*4);
    float*          c1     = (float*)alloc((size_t)R_*H_*4);
    unsigned short* WxT    = (unsigned short*)alloc((size_t)N2*KD*2);
    unsigned short* WcatT  = (unsigned short*)alloc((size_t)N2*KD*2);
    float*          bcat   = (float*)alloc((size_t)N2*4);
    unsigned short* xb     = (unsigned short*)alloc((size_t)R_*KD*2);
    unsigned short* hb     = (unsigned short*)alloc((size_t)R_*KD*2);
    int*            msk    = (int*)alloc((size_t)NST*R_*4);
    int*            rnk    = (int*)alloc((size_t)NST*R_*4);
    int*            cnt    = (int*)alloc((size_t)3*NST*R_*4);
    int*            off    = (int*)alloc((size_t)3*NST*R_*4);
    int*            cur    = (int*)alloc((size_t)3*NST*R_*4);
    int*            ent    = (int*)alloc((size_t)3*NST*R_*4);
    int*            flags  = (int*)alloc(256);
    int*            bar    = (int*)alloc(256);
    float*          out    = (float*)d_out;   // fp32 output (verified r4)

    hipLaunchKernelGGL(probe_all, dim3(17), dim3(1024), 0, stream,
                       d_in[2], d_in[3], d_in[4], d_in[5], d_in[6], d_in[7], d_in[8],
                       d_in[9], d_in[10], d_in[11], d_in[12], d_in[13], d_in[14],
                       d_in[15], d_in[16], input_ids, tree, flags);
    hipLaunchKernelGGL(rank_pack, dim3(NB2), dim3(512), 0, stream,
                       d_in[3], d_in[8],
                       d_in[4], d_in[6], d_in[9], d_in[11], d_in[13], d_in[15],
                       d_in[5], d_in[7], d_in[10], d_in[12], d_in[14], d_in[16],
                       input_ids, d_in[2], tree,
                       WxT, WcatT, bcat, xb, h0, msk, rnk, cnt, flags, bar);
    hipLaunchKernelGGL(csr_scan, dim3(NST, 3), dim3(1024), 0, stream, cnt, off, cur);
    hipLaunchKernelGGL(csr_fill, dim3(NST), dim3(512), 0, stream, tree, cur, ent, flags);

    // single fused kernel for the whole step chain (512 blocks x 256 thr, 2/CU resident)
    hipLaunchKernelGGL(chain_all, dim3(NBLK), dim3(256), 0, stream,
                       xb, WxT, WcatT, bcat, XO, T, h0, c0, h1, c1, hb, out,
                       msk, rnk, cnt, off, ent, bar);
}

// Round 4
// 305.957 us; speedup vs baseline: 3.6974x; 3.6974x over previous
//
#include <hip/hip_runtime.h>
#include <hip/hip_bf16.h>

#define B_ 8
#define S_ 128
#define H_ 512
#define E_ 512
#define NST 8
#define R_ 1024
#define N2 2048
#define KD 512
#define LDA 72          // LDS row pitch in shorts (fragment ds_read_b128: 2-way = free)
#define NBLK 512        // chain grid: 2 blocks/CU x 256 CUs, co-resident by construction
#define GRP 64          // blocks per barrier group (8 groups)

typedef __hip_bfloat16 bf16;
typedef __attribute__((ext_vector_type(8))) short v8s;
typedef __attribute__((ext_vector_type(4))) float v4f;
typedef unsigned long long u64;

__device__ __forceinline__ float sigm(float x){ return 1.0f/(1.0f + expf(-x)); }
__device__ __forceinline__ float load_in(const void* p, long long i, int isb){
    return isb ? __bfloat162float(((const bf16*)p)[i]) : ((const float*)p)[i];
}
__device__ __forceinline__ int idx_read(const int* p, int j, int is64){
    return is64 ? p[2*j] : p[j];
}
__device__ __forceinline__ unsigned short f2b(float v){
    bf16 b = __float2bfloat16(v);
    return *(unsigned short*)&b;
}

// ---- MALL-coherent (agent-scope, L1/L2-bypassing) access helpers ----
// All cross-phase tensors (T, XO, hb, h/c state) go through these; the grid
// barrier then needs NO cache-maintenance ops (the r3 983us fence storm).
__device__ __forceinline__ float2 vload2(const float* p){
    union { u64 u; float2 f; } c;
    c.u = __hip_atomic_load((const u64*)p, __ATOMIC_RELAXED, __HIP_MEMORY_SCOPE_AGENT);
    return c.f;
}
__device__ __forceinline__ void vstore2(float* p, float2 v){
    union { float2 f; u64 u; } c; c.f = v;
    __hip_atomic_store((u64*)p, c.u, __ATOMIC_RELAXED, __HIP_MEMORY_SCOPE_AGENT);
}
__device__ __forceinline__ void vstore1(float* p, float v){
    __hip_atomic_store(p, v, __ATOMIC_RELAXED, __HIP_MEMORY_SCOPE_AGENT);
}
__device__ __forceinline__ void vstore_hb2(unsigned short* p, unsigned short a, unsigned short b){
    unsigned int u = (unsigned)a | ((unsigned)b << 16);
    __hip_atomic_store((unsigned int*)p, u, __ATOMIC_RELAXED, __HIP_MEMORY_SCOPE_AGENT);
}
__device__ __forceinline__ v8s vload16(const unsigned short* p){
    union { u64 u[2]; v8s v; } c;
    c.u[0] = __hip_atomic_load((const u64*)p,     __ATOMIC_RELAXED, __HIP_MEMORY_SCOPE_AGENT);
    c.u[1] = __hip_atomic_load(((const u64*)p)+1, __ATOMIC_RELAXED, __HIP_MEMORY_SCOPE_AGENT);
    return c.v;
}

// Two-level counter-only grid barrier. bar layout (64-int / 256B stride):
//   bar[0]        global counter (+GRP per group)
//   bar[64*(1+g)] group-g arrival (monotonic, +1/block/barrier)
//   bar[64*(9+g)] group-g done    (monotonic, +1/barrier by leader)
// __syncthreads() drains vmcnt before s_barrier (compiler-guaranteed), so all
// threads' MALL stores are acked before any arrival is published.
__device__ __forceinline__ void gsync(int* bar, int gen){
    __syncthreads();
    if (threadIdx.x == 0){
        int g = blockIdx.x >> 6;
        int* ga = bar + 64*(1+g);
        int* gd = bar + 64*(9+g);
        int old = __hip_atomic_fetch_add(ga, 1, __ATOMIC_RELAXED, __HIP_MEMORY_SCOPE_AGENT);
        if (old + 1 == GRP*gen){
            __hip_atomic_fetch_add(bar, GRP, __ATOMIC_RELAXED, __HIP_MEMORY_SCOPE_AGENT);
            while (__hip_atomic_load(bar, __ATOMIC_RELAXED, __HIP_MEMORY_SCOPE_AGENT) < NBLK*gen)
                __builtin_amdgcn_s_sleep(4);
            __hip_atomic_fetch_add(gd, 1, __ATOMIC_RELAXED, __HIP_MEMORY_SCOPE_AGENT);
        } else {
            while (__hip_atomic_load(gd, __ATOMIC_RELAXED, __HIP_MEMORY_SCOPE_AGENT) < gen)
                __builtin_amdgcn_s_sleep(4);
        }
    }
    __syncthreads();
}

// ---- K1: dtype probes (bid 0..14 float tensors, 15/16 int tensors) ----
__global__ void probe_all(const void* t0, const void* t1, const void* t2, const void* t3,
                          const void* t4, const void* t5, const void* t6, const void* t7,
                          const void* t8, const void* t9, const void* t10, const void* t11,
                          const void* t12, const void* t13, const void* t14,
                          const int* __restrict__ ids, const int* __restrict__ tree,
                          int* __restrict__ flags){
    const void* ts[15] = {t0,t1,t2,t3,t4,t5,t6,t7,t8,t9,t10,t11,t12,t13,t14};
    int bid = blockIdx.x, t = threadIdx.x;   // 1024 threads
    int bad = 0;
    if (bid < 15){
        if (t < 512){
            unsigned short u = ((const unsigned short*)ts[bid])[t];
            bad = (((u >> 7) & 0xFF) >= 140);
        }
    } else {
        const int* p = (bid == 15) ? ids : tree;
        int n = (bid == 15) ? 1024 : 2048;
        for (int j = t; j < n; j += 1024)
            if (j & 1) bad |= (p[j] != 0);
    }
    unsigned long long bl = __ballot(bad);
    __shared__ int acc[16];
    if ((t & 63) == 0) acc[t >> 6] = (bl != 0ull) ? 1 : 0;
    __syncthreads();
    if (t == 0){
        int any = 0;
        for (int w = 0; w < 16; ++w) any |= acc[w];
        flags[(bid < 15) ? bid : (16 + bid - 15)] = any ? 0 : 1;
    }
}

// ---- K2: rank+CSR-count (bid<8) + all one-time packs + zero-init (512 thr) ----
#define NB2 320
#define GS2 (NB2*512)
__global__ __launch_bounds__(512)
void rank_pack(const void* __restrict__ Wioux, const void* __restrict__ Wfx,
               const void* __restrict__ Wr, const void* __restrict__ Wl,
               const void* __restrict__ W0, const void* __restrict__ W1,
               const void* __restrict__ W2, const void* __restrict__ W3,
               const void* __restrict__ br, const void* __restrict__ bl,
               const void* __restrict__ b0, const void* __restrict__ b1,
               const void* __restrict__ b2, const void* __restrict__ b3,
               const int* __restrict__ ids, const void* __restrict__ emb,
               const int* __restrict__ tree,
               unsigned short* __restrict__ WxT, unsigned short* __restrict__ WcatT,
               float* __restrict__ bcat, unsigned short* __restrict__ xb,
               float* __restrict__ h0,
               int* __restrict__ msk, int* __restrict__ rnk, int* __restrict__ cnt,
               const int* __restrict__ flags, int* __restrict__ bar){
    int bid = blockIdx.x, tid = threadIdx.x;
    int is64 = flags[17];
    if (bid == 0){                         // reset chain barrier block (replay-safe)
        for (int i = tid; i < 64*17; i += 512) bar[i] = 0;
    }
    if (bid < 8){
        int st = bid;
        for (int c = tid; c < R_; c += 512){
            cnt[(0*NST + st)*R_ + c] = 0;
            cnt[(1*NST + st)*R_ + c] = 0;
            cnt[(2*NST + st)*R_ + c] = 0;
        }
        __syncthreads();
        __shared__ int wt[8];
        int runbase = 0;
        for (int ch = 0; ch < 2; ++ch){
            int t = ch*512 + tid;
            int b = t >> 7, s = t & 127;
            int base = (b*NST + st)*3*S_;
            int d0 = idx_read(tree, base + s, is64);
            int rd = (b<<7) + d0;
            int rr = (b<<7) + idx_read(tree, base + S_ + s, is64);
            int rl = (b<<7) + idx_read(tree, base + 2*S_ + s, is64);
            int m = (d0 != 0) ? 1 : 0;
            unsigned long long bal = __ballot(m);
            int lane = tid & 63, wv = tid >> 6;
            if (lane == 0) wt[wv] = __popcll(bal);
            __syncthreads();
            int bp = runbase, tot = 0;
            for (int w = 0; w < wv; ++w) bp += wt[w];
            for (int w = 0; w < 8; ++w) tot += wt[w];
            int rank = bp + __popcll(bal & ((1ull << lane) - 1ull));
            msk[st*R_ + t] = m;
            rnk[st*R_ + t] = m ? rank : 0;
            atomicAdd(&cnt[(0*NST + st)*R_ + rr], 1);
            atomicAdd(&cnt[(1*NST + st)*R_ + rl], 1);
            atomicAdd(&cnt[(2*NST + st)*R_ + rd], 1);
            runbase += tot;
            __syncthreads();
        }
    }
    int gt = bid*512 + tid;
    {   // WxT: 2048 n x 64 k-groups
        int f_wx = flags[1], f_wf = flags[6];
        for (int u = gt; u < 131072; u += GS2){
            int n = u >> 6, k0 = (u & 63)*8;
            unsigned short tmp[8];
            #pragma unroll
            for (int i = 0; i < 8; ++i){
                float v = (n < 1536) ? load_in(Wioux, (long long)(k0+i)*1536 + n, f_wx)
                                     : load_in(Wfx,   (long long)(k0+i)*512 + (n-1536), f_wf);
                tmp[i] = f2b(v);
            }
            *(v8s*)&WxT[(size_t)n*KD + k0] = *(v8s*)tmp;
        }
    }
    {   // WcatT
        int fWr=flags[2], fWl=flags[4], fW0=flags[7], fW1=flags[9], fW2=flags[11], fW3=flags[13];
        for (int u = gt; u < 131072; u += GS2){
            int n = u >> 6, k0 = (u & 63)*8;
            unsigned short tmp[8];
            #pragma unroll
            for (int i = 0; i < 8; ++i){
                long long k = k0 + i;
                float v;
                if      (n <  512) v = load_in(Wr, k*1536 + n, fWr);
                else if (n < 1024) v = load_in(Wl, k*1536 + (n-512), fWl);
                else if (n < 1536) { int c = n-1024; v = load_in(W0, k*512+c, fW0) + load_in(W1, k*512+c, fW1); }
                else               { int c = n-1536; v = load_in(W2, k*512+c, fW2) + load_in(W3, k*512+c, fW3); }
                tmp[i] = f2b(v);
            }
            *(v8s*)&WcatT[(size_t)n*KD + k0] = *(v8s*)tmp;
        }
    }
    {   // bcat
        int fbr=flags[3], fbl=flags[5], fb0=flags[8], fb1=flags[10], fb2=flags[12], fb3=flags[14];
        for (int n = gt; n < 2048; n += GS2){
            float v;
            if      (n <  512) v = load_in(br, n, fbr);
            else if (n < 1024) v = load_in(bl, n-512, fbl);
            else if (n < 1536) v = load_in(b0, n-1024, fb0) + load_in(b1, n-1024, fb1);
            else               v = load_in(b2, n-1536, fb2) + load_in(b3, n-1536, fb3);
            bcat[n] = v;
        }
    }
    {   // xb: 1024 rows x 64 groups
        int f_emb = flags[0], i64i = flags[16];
        for (int u = gt; u < 65536; u += GS2){
            int r = u >> 6, c0 = (u & 63)*8;
            long long base = (long long)idx_read(ids, r, i64i)*E_ + c0;
            unsigned short tmp[8];
            #pragma unroll
            for (int i = 0; i < 8; ++i) tmp[i] = f2b(load_in(emb, base + i, f_emb));
            *(v8s*)&xb[(size_t)r*KD + c0] = *(v8s*)tmp;
        }
    }
    for (int u = gt; u < 262144; u += GS2)   // zero h0+c0 (contiguous 4 MB)
        ((float4*)h0)[u] = make_float4(0.f,0.f,0.f,0.f);
}

// ---- K3: CSR scans ----
__global__ void csr_scan(const int* __restrict__ cnt, int* __restrict__ off,
                         int* __restrict__ cur){
    int st = blockIdx.x, a = blockIdx.y;
    int t = threadIdx.x;   // 1024
    int base = (a*NST + st)*R_;
    __shared__ int sh[R_];
    int v = cnt[base + t];
    sh[t] = v;
    __syncthreads();
    for (int d = 1; d < R_; d <<= 1){
        int x = (t >= d) ? sh[t - d] : 0;
        __syncthreads();
        sh[t] += x;
        __syncthreads();
    }
    int excl = sh[t] - v;
    off[base + t] = excl;
    cur[base + t] = excl;
}

// ---- K4: CSR fill ----
__global__ __launch_bounds__(512)
void csr_fill(const int* __restrict__ tree, int* __restrict__ cur,
              int* __restrict__ ent, const int* __restrict__ flags){
    int is64 = flags[17];
    int st = blockIdx.x;
    for (int ch = 0; ch < 2; ++ch){
        int t = ch*512 + threadIdx.x;
        int b = t >> 7, s = t & 127;
        int base = (b*NST + st)*3*S_;
        int rd = (b<<7) + idx_read(tree, base + s, is64);
        int rr = (b<<7) + idx_read(tree, base + S_ + s, is64);
        int rl = (b<<7) + idx_read(tree, base + 2*S_ + s, is64);
        int p0 = atomicAdd(&cur[(0*NST + st)*R_ + rr], 1);
        ent[(0*NST + st)*R_ + p0] = t;
        int p1 = atomicAdd(&cur[(1*NST + st)*R_ + rl], 1);
        ent[(1*NST + st)*R_ + p1] = t;
        int p2 = atomicAdd(&cur[(2*NST + st)*R_ + rd], 1);
        ent[(2*NST + st)*R_ + p2] = t | (rr << 10) | (rl << 20);
    }
}

// ---- GEMM phase: C[1024][2048] = A@BT^T (+bias) ----
// A (hb/xb) read via MALL-coherent loads (cross-phase data); B (immutable
// weights) via normal cached loads (keeps L2 reuse); C written MALL-coherent.
__device__ __forceinline__ void gemm_phase(const unsigned short* __restrict__ A,
               const unsigned short* __restrict__ BT,
               const float* __restrict__ bias,
               float* __restrict__ C,
               short* __restrict__ As, short* __restrict__ Bs)
{
    int bid = blockIdx.x;
    int bn = (bid & 7)*4 + ((bid >> 3) & 3);   // 0..31, 4 panels per XCD-ish group
    int bm = bid >> 5;                          // 0..15
    int tid = threadIdx.x;
    int lane = tid & 63, wave = tid >> 6;
    int wm = wave & 1, wn = wave >> 1;
    int lm = lane & 15, quad = lane >> 4;
    v4f acc[2][2];
    #pragma unroll
    for (int i=0;i<2;++i)
        #pragma unroll
        for (int j=0;j<2;++j) acc[i][j] = (v4f)0.0f;

    int srow = tid >> 3, sg = (tid & 7)*8;
    const unsigned short* Ab = A  + (size_t)(bm*64)*KD;
    const unsigned short* Bb = BT + (size_t)(bn*64)*KD;
    v8s pa[2], pb[2];
    #pragma unroll
    for (int j=0;j<2;++j){
        pa[j] = vload16(Ab + (size_t)(j*32+srow)*KD + sg);
        pb[j] = *(const v8s*)(Bb + (size_t)(j*32+srow)*KD + sg);
    }
    for (int k0 = 0; k0 < KD; k0 += 64){
        #pragma unroll
        for (int j=0;j<2;++j){
            *(v8s*)&As[(j*32+srow)*LDA + sg] = pa[j];
            *(v8s*)&Bs[(j*32+srow)*LDA + sg] = pb[j];
        }
        __syncthreads();
        int k1 = k0 + 64;
        if (k1 < KD){
            #pragma unroll
            for (int j=0;j<2;++j){
                pa[j] = vload16(Ab + (size_t)(j*32+srow)*KD + k1 + sg);
                pb[j] = *(const v8s*)(Bb + (size_t)(j*32+srow)*KD + k1 + sg);
            }
        }
        #pragma unroll
        for (int kk = 0; kk < 64; kk += 32){
            v8s af[2], bf[2];
            #pragma unroll
            for (int i=0;i<2;++i){
                af[i] = *(const v8s*)&As[(wm*32 + i*16 + lm)*LDA + kk + quad*8];
                bf[i] = *(const v8s*)&Bs[(wn*32 + i*16 + lm)*LDA + kk + quad*8];
            }
            #pragma unroll
            for (int i=0;i<2;++i)
                #pragma unroll
                for (int j=0;j<2;++j)
                    acc[i][j] = __builtin_amdgcn_mfma_f32_16x16x32_bf16(af[i], bf[j], acc[i][j], 0, 0, 0);
        }
        __syncthreads();
    }
    #pragma unroll
    for (int j=0;j<2;++j){
        int n = bn*64 + wn*32 + j*16 + lm;
        float bv = bias ? bias[n] : 0.0f;
        #pragma unroll
        for (int i=0;i<2;++i){
            int m0 = bm*64 + wm*32 + i*16 + quad*4;
            #pragma unroll
            for (int rg = 0; rg < 4; ++rg)
                vstore1(&C[(size_t)(m0+rg)*N2 + n], acc[i][j][rg] + bv);
        }
    }
}

// ---- epi phase: CSR-gathered scatters + gates + masked-scatter ----
// 512 blocks x 256 threads: 2 rows/block, 2 ADJACENT cols/thread (c0=2*tid)
// so every cross-phase access is one 8B/4B MALL-coherent op.
// tstr=0 with T=bcat implements the step-0 (h=0 => T = bias broadcast) shortcut.
__device__ __forceinline__ void epi_phase(const float* __restrict__ XO,
              const float* __restrict__ T, int tstr,
              const float* __restrict__ hc, const float* __restrict__ cc,
              float* __restrict__ hn, float* __restrict__ cn,
              unsigned short* __restrict__ hb, float* __restrict__ out,
              const int* __restrict__ msk, const int* __restrict__ rnk,
              const int* __restrict__ cnt, const int* __restrict__ off,
              const int* __restrict__ ent, int st, int last)
{
    int tid = threadIdx.x;
    int c0 = tid*2;
    #pragma unroll
    for (int rr2 = 0; rr2 < 2; ++rr2){
        int r = blockIdx.x*2 + rr2;
        if (!msk[st*R_ + r]){
            float2 hv = vload2(&hc[(size_t)r*H_ + c0]);
            if (last){
                out[(size_t)r*H_ + c0]     = hv.x;
                out[(size_t)r*H_ + c0 + 1] = hv.y;
            } else {
                vstore2(&hn[(size_t)r*H_ + c0], hv);
                float2 cv = vload2(&cc[(size_t)r*H_ + c0]);
                vstore2(&cn[(size_t)r*H_ + c0], cv);
                vstore_hb2(&hb[(size_t)r*KD + c0], f2b(hv.x), f2b(hv.y));
            }
            continue;
        }
        int j = rnk[st*R_ + r];
        int bR = off[(0*NST+st)*R_ + j], dR = cnt[(0*NST+st)*R_ + j];
        int bL = off[(1*NST+st)*R_ + j], dL = cnt[(1*NST+st)*R_ + j];
        int bD = off[(2*NST+st)*R_ + j], dD = cnt[(2*NST+st)*R_ + j];
        const int* eR = ent + (0*NST+st)*R_ + bR;
        const int* eL = ent + (1*NST+st)*R_ + bL;
        const int* eD = ent + (2*NST+st)*R_ + bD;
        const float* xo = XO + (size_t)j*N2;
        float scv0 = 0.f, scv1 = 0.f;
        for (int e = 0; e < dR; ++e){
            float2 t = vload2(&T[(size_t)eR[e]*tstr + c0]);
            scv0 += t.x; scv1 += t.y;
        }
        for (int e = 0; e < dL; ++e){
            float2 t = vload2(&T[(size_t)eL[e]*tstr + 512 + c0]);
            scv0 += t.x; scv1 += t.y;
        }
        float2 fx = vload2(&xo[1536 + c0]);
        float csc0 = 0.f, csc1 = 0.f;
        for (int e = 0; e < dD; ++e){
            int pk = eD[e];
            int s  = pk & 1023, ra = (pk >> 10) & 1023, rb = (pk >> 20) & 1023;
            float2 ta = vload2(&T[(size_t)ra*tstr + 1024 + c0]);
            float2 tb = vload2(&T[(size_t)rb*tstr + 1536 + c0]);
            float2 cv = vload2(&cc[(size_t)s*H_ + c0]);
            float f0 = sigm(fx.x + ta.x + tb.x);
            float f1 = sigm(fx.y + ta.y + tb.y);
            csc0 += f0 * cv.x;
            csc1 += f1 * cv.y;
        }
        float2 xi = vload2(&xo[c0]);
        float2 xq = vload2(&xo[512 + c0]);
        float2 xu = vload2(&xo[1024 + c0]);
        float ig0 = sigm(xi.x + scv0), ig1 = sigm(xi.y + scv1);
        float og0 = sigm(xq.x), og1 = sigm(xq.y);
        float ug0 = tanhf(xu.x), ug1 = tanhf(xu.y);
        float cf0 = ig0*ug0 + csc0, cf1 = ig1*ug1 + csc1;
        float hf0 = og0 * tanhf(cf0), hf1 = og1 * tanhf(cf1);
        if (last){
            out[(size_t)r*H_ + c0]     = hf0;
            out[(size_t)r*H_ + c0 + 1] = hf1;
        } else {
            vstore2(&hn[(size_t)r*H_ + c0], make_float2(hf0, hf1));
            vstore2(&cn[(size_t)r*H_ + c0], make_float2(cf0, cf1));
            vstore_hb2(&hb[(size_t)r*KD + c0], f2b(hf0), f2b(hf1));
        }
    }
}

// ---- fused chain: XO GEMM + epi0 + 7x(GEMM, epi); counter-only grid barriers ----
__global__ __launch_bounds__(256, 2)
void chain_all(const unsigned short* __restrict__ xb,
               const unsigned short* __restrict__ WxT,
               const unsigned short* __restrict__ WcatT,
               const float* __restrict__ bcat,
               float* __restrict__ XO, float* __restrict__ T,
               float* __restrict__ h0, float* __restrict__ c0,
               float* __restrict__ h1, float* __restrict__ c1,
               unsigned short* __restrict__ hb, float* __restrict__ out,
               const int* __restrict__ msk, const int* __restrict__ rnk,
               const int* __restrict__ cnt, const int* __restrict__ off,
               const int* __restrict__ ent, int* bar)
{
    __shared__ short As[64*LDA];
    __shared__ short Bs[64*LDA];
    int gen = 0;

    // phase 0: XO = xb @ WxT^T (no bias)
    gemm_phase(xb, WxT, (const float*)nullptr, XO, As, Bs);
    gsync(bar, ++gen);
    // step 0: h==0 -> T is the bias broadcast; no GEMM needed (tstr=0, T=bcat)
    epi_phase(XO, bcat, 0, h0, c0, h1, c1, hb, out, msk, rnk, cnt, off, ent, 0, 0);
    gsync(bar, ++gen);

    for (int st = 1; st < NST; ++st){
        const float* hcp = (st & 1) ? h1 : h0;
        const float* ccp = (st & 1) ? c1 : c0;
        float* hnp = (st & 1) ? h0 : h1;
        float* cnp = (st & 1) ? c0 : c1;
        gemm_phase(hb, WcatT, bcat, T, As, Bs);
        gsync(bar, ++gen);
        epi_phase(XO, T, N2, hcp, ccp, hnp, cnp, hb, out,
                  msk, rnk, cnt, off, ent, st, (st == NST-1) ? 1 : 0);
        if (st < NST-1) gsync(bar, ++gen);
    }
}

extern "C" void kernel_launch(void* const* d_in, const int* in_sizes, int n_in,
                              void* d_out, int out_size, void* d_ws, size_t ws_size,
                              hipStream_t stream) {
    const int* input_ids = (const int*)d_in[0];
    const int* tree      = (const int*)d_in[1];

    char* wp = (char*)d_ws;
    auto alloc = [&](size_t bytes) -> void* {
        void* q = (void*)wp;
        wp += (bytes + 255) & ~(size_t)255;
        return q;
    };
    float*          XO     = (float*)alloc((size_t)R_*N2*4);
    float*          T      = (float*)alloc((size_t)R_*N2*4);
    float*          h0     = (float*)alloc((size_t)R_*H_*4);   // contiguous with c0
    float*          c0     = (float*)alloc((size_t)R_*H_*4);
    float*          h1     = (float*)alloc((size_t)R_*H_*4);
    float*          c1     = (float*)alloc((size_t)R_*H_*4);
    unsigned short* WxT    = (unsigned short*)alloc((size_t)N2*KD*2);
    unsigned short* WcatT  = (unsigned short*)alloc((size_t)N2*KD*2);
    float*          bcat   = (float*)alloc((size_t)N2*4);
    unsigned short* xb     = (unsigned short*)alloc((size_t)R_*KD*2);
    unsigned short* hb     = (unsigned short*)alloc((size_t)R_*KD*2);
    int*            msk    = (int*)alloc((size_t)NST*R_*4);
    int*            rnk    = (int*)alloc((size_t)NST*R_*4);
    int*            cnt    = (int*)alloc((size_t)3*NST*R_*4);
    int*            off    = (int*)alloc((size_t)3*NST*R_*4);
    int*            cur    = (int*)alloc((size_t)3*NST*R_*4);
    int*            ent    = (int*)alloc((size_t)3*NST*R_*4);
    int*            flags  = (int*)alloc(256);
    int*            bar    = (int*)alloc(8192);
    float*          out    = (float*)d_out;   // fp32 output (verified r4)

    hipLaunchKernelGGL(probe_all, dim3(17), dim3(1024), 0, stream,
                       d_in[2], d_in[3], d_in[4], d_in[5], d_in[6], d_in[7], d_in[8],
                       d_in[9], d_in[10], d_in[11], d_in[12], d_in[13], d_in[14],
                       d_in[15], d_in[16], input_ids, tree, flags);
    hipLaunchKernelGGL(rank_pack, dim3(NB2), dim3(512), 0, stream,
                       d_in[3], d_in[8],
                       d_in[4], d_in[6], d_in[9], d_in[11], d_in[13], d_in[15],
                       d_in[5], d_in[7], d_in[10], d_in[12], d_in[14], d_in[16],
                       input_ids, d_in[2], tree,
                       WxT, WcatT, bcat, xb, h0, msk, rnk, cnt, flags, bar);
    hipLaunchKernelGGL(csr_scan, dim3(NST, 3), dim3(1024), 0, stream, cnt, off, cur);
    hipLaunchKernelGGL(csr_fill, dim3(NST), dim3(512), 0, stream, tree, cur, ent, flags);

    // single fused kernel for the whole step chain (512 blocks x 256 thr, 2/CU resident)
    hipLaunchKernelGGL(chain_all, dim3(NBLK), dim3(256), 0, stream,
                       xb, WxT, WcatT, bcat, XO, T, h0, c0, h1, c1, hb, out,
                       msk, rnk, cnt, off, ent, bar);
}

// Round 7
// 295.536 us; speedup vs baseline: 3.8278x; 1.0353x over previous
//
#include <hip/hip_runtime.h>
#include <hip/hip_bf16.h>

#define B_ 8
#define S_ 128
#define H_ 512
#define E_ 512
#define NST 8
#define R_ 1024
#define N2 2048
#define KD 512
#define LDA 72          // LDS row pitch in shorts (fragment ds_read_b128: 2-way = free)
#define NBLK 512        // chain grid: 2 blocks/CU x 256 CUs, co-resident by construction
#define GRP 64          // blocks per barrier group (8 groups)

typedef __hip_bfloat16 bf16;
typedef __attribute__((ext_vector_type(8))) short v8s;
typedef __attribute__((ext_vector_type(4))) float v4f;
typedef unsigned long long u64;

__device__ __forceinline__ float sigm(float x){ return 1.0f/(1.0f + expf(-x)); }
__device__ __forceinline__ float load_in(const void* p, long long i, int isb){
    return isb ? __bfloat162float(((const bf16*)p)[i]) : ((const float*)p)[i];
}
__device__ __forceinline__ int idx_read(const int* p, int j, int is64){
    return is64 ? p[2*j] : p[j];
}
__device__ __forceinline__ unsigned short f2b(float v){
    bf16 b = __float2bfloat16(v);
    return *(unsigned short*)&b;
}

// ---- MALL-coherent (agent-scope, L1/L2-bypassing) access helpers ----
// All cross-phase tensors (T, XO, hb, h/c state) go through these; the grid
// barrier then needs NO cache-maintenance ops (the r3 983us fence storm).
__device__ __forceinline__ float vload1f(const float* p){
    return __hip_atomic_load(p, __ATOMIC_RELAXED, __HIP_MEMORY_SCOPE_AGENT);
}
__device__ __forceinline__ void vstore1(float* p, float v){
    __hip_atomic_store(p, v, __ATOMIC_RELAXED, __HIP_MEMORY_SCOPE_AGENT);
}
__device__ __forceinline__ void vstore_hb2(unsigned short* p, unsigned short a, unsigned short b){
    unsigned int u = (unsigned)a | ((unsigned)b << 16);
    __hip_atomic_store((unsigned int*)p, u, __ATOMIC_RELAXED, __HIP_MEMORY_SCOPE_AGENT);
}
__device__ __forceinline__ v8s vload16(const unsigned short* p){
    union { u64 u[2]; v8s v; } c;
    c.u[0] = __hip_atomic_load((const u64*)p,     __ATOMIC_RELAXED, __HIP_MEMORY_SCOPE_AGENT);
    c.u[1] = __hip_atomic_load(((const u64*)p)+1, __ATOMIC_RELAXED, __HIP_MEMORY_SCOPE_AGENT);
    return c.v;
}

// Two-level counter-only grid barrier. bar layout (64-int / 256B stride):
//   bar[0]        global counter (+GRP per group)
//   bar[64*(1+g)] group-g arrival (monotonic, +1/block/barrier)
//   bar[64*(9+g)] group-g done    (monotonic, +1/barrier by leader)
__device__ __forceinline__ void gsync(int* bar, int gen){
    __syncthreads();
    if (threadIdx.x == 0){
        int g = blockIdx.x >> 6;
        int* ga = bar + 64*(1+g);
        int* gd = bar + 64*(9+g);
        int old = __hip_atomic_fetch_add(ga, 1, __ATOMIC_RELAXED, __HIP_MEMORY_SCOPE_AGENT);
        if (old + 1 == GRP*gen){
            __hip_atomic_fetch_add(bar, GRP, __ATOMIC_RELAXED, __HIP_MEMORY_SCOPE_AGENT);
            while (__hip_atomic_load(bar, __ATOMIC_RELAXED, __HIP_MEMORY_SCOPE_AGENT) < NBLK*gen)
                __builtin_amdgcn_s_sleep(4);
            __hip_atomic_fetch_add(gd, 1, __ATOMIC_RELAXED, __HIP_MEMORY_SCOPE_AGENT);
        } else {
            while (__hip_atomic_load(gd, __ATOMIC_RELAXED, __HIP_MEMORY_SCOPE_AGENT) < gen)
                __builtin_amdgcn_s_sleep(4);
        }
    }
    __syncthreads();
}

// ---- K1: dtype probes (bid 0..14 float tensors, 15/16 int tensors) ----
__global__ void probe_all(const void* t0, const void* t1, const void* t2, const void* t3,
                          const void* t4, const void* t5, const void* t6, const void* t7,
                          const void* t8, const void* t9, const void* t10, const void* t11,
                          const void* t12, const void* t13, const void* t14,
                          const int* __restrict__ ids, const int* __restrict__ tree,
                          int* __restrict__ flags){
    const void* ts[15] = {t0,t1,t2,t3,t4,t5,t6,t7,t8,t9,t10,t11,t12,t13,t14};
    int bid = blockIdx.x, t = threadIdx.x;   // 1024 threads
    int bad = 0;
    if (bid < 15){
        if (t < 512){
            unsigned short u = ((const unsigned short*)ts[bid])[t];
            bad = (((u >> 7) & 0xFF) >= 140);
        }
    } else {
        const int* p = (bid == 15) ? ids : tree;
        int n = (bid == 15) ? 1024 : 2048;
        for (int j = t; j < n; j += 1024)
            if (j & 1) bad |= (p[j] != 0);
    }
    unsigned long long bl = __ballot(bad);
    __shared__ int acc[16];
    if ((t & 63) == 0) acc[t >> 6] = (bl != 0ull) ? 1 : 0;
    __syncthreads();
    if (t == 0){
        int any = 0;
        for (int w = 0; w < 16; ++w) any |= acc[w];
        flags[(bid < 15) ? bid : (16 + bid - 15)] = any ? 0 : 1;
    }
}

// ---- K2: rank+CSR-count (bid<8) + all one-time packs + zero-init (512 thr) ----
#define NB2 320
#define GS2 (NB2*512)
__global__ __launch_bounds__(512)
void rank_pack(const void* __restrict__ Wioux, const void* __restrict__ Wfx,
               const void* __restrict__ Wr, const void* __restrict__ Wl,
               const void* __restrict__ W0, const void* __restrict__ W1,
               const void* __restrict__ W2, const void* __restrict__ W3,
               const void* __restrict__ br, const void* __restrict__ bl,
               const void* __restrict__ b0, const void* __restrict__ b1,
               const void* __restrict__ b2, const void* __restrict__ b3,
               const int* __restrict__ ids, const void* __restrict__ emb,
               const int* __restrict__ tree,
               unsigned short* __restrict__ WxT, unsigned short* __restrict__ WcatT,
               float* __restrict__ bcat, unsigned short* __restrict__ xb,
               float* __restrict__ h0,
               int* __restrict__ msk, int* __restrict__ rnk, int* __restrict__ cnt,
               const int* __restrict__ flags, int* __restrict__ bar){
    int bid = blockIdx.x, tid = threadIdx.x;
    int is64 = flags[17];
    if (bid == 0){                         // reset chain barrier block (replay-safe)
        for (int i = tid; i < 64*17; i += 512) bar[i] = 0;
    }
    if (bid < 8){
        int st = bid;
        for (int c = tid; c < R_; c += 512){
            cnt[(0*NST + st)*R_ + c] = 0;
            cnt[(1*NST + st)*R_ + c] = 0;
            cnt[(2*NST + st)*R_ + c] = 0;
        }
        __syncthreads();
        __shared__ int wt[8];
        int runbase = 0;
        for (int ch = 0; ch < 2; ++ch){
            int t = ch*512 + tid;
            int b = t >> 7, s = t & 127;
            int base = (b*NST + st)*3*S_;
            int d0 = idx_read(tree, base + s, is64);
            int rd = (b<<7) + d0;
            int rr = (b<<7) + idx_read(tree, base + S_ + s, is64);
            int rl = (b<<7) + idx_read(tree, base + 2*S_ + s, is64);
            int m = (d0 != 0) ? 1 : 0;
            unsigned long long bal = __ballot(m);
            int lane = tid & 63, wv = tid >> 6;
            if (lane == 0) wt[wv] = __popcll(bal);
            __syncthreads();
            int bp = runbase, tot = 0;
            for (int w = 0; w < wv; ++w) bp += wt[w];
            for (int w = 0; w < 8; ++w) tot += wt[w];
            int rank = bp + __popcll(bal & ((1ull << lane) - 1ull));
            msk[st*R_ + t] = m;
            rnk[st*R_ + t] = m ? rank : 0;
            atomicAdd(&cnt[(0*NST + st)*R_ + rr], 1);
            atomicAdd(&cnt[(1*NST + st)*R_ + rl], 1);
            atomicAdd(&cnt[(2*NST + st)*R_ + rd], 1);
            runbase += tot;
            __syncthreads();
        }
    }
    int gt = bid*512 + tid;
    {   // WxT: 2048 n x 64 k-groups
        int f_wx = flags[1], f_wf = flags[6];
        for (int u = gt; u < 131072; u += GS2){
            int n = u >> 6, k0 = (u & 63)*8;
            unsigned short tmp[8];
            #pragma unroll
            for (int i = 0; i < 8; ++i){
                float v = (n < 1536) ? load_in(Wioux, (long long)(k0+i)*1536 + n, f_wx)
                                     : load_in(Wfx,   (long long)(k0+i)*512 + (n-1536), f_wf);
                tmp[i] = f2b(v);
            }
            *(v8s*)&WxT[(size_t)n*KD + k0] = *(v8s*)tmp;
        }
    }
    {   // WcatT
        int fWr=flags[2], fWl=flags[4], fW0=flags[7], fW1=flags[9], fW2=flags[11], fW3=flags[13];
        for (int u = gt; u < 131072; u += GS2){
            int n = u >> 6, k0 = (u & 63)*8;
            unsigned short tmp[8];
            #pragma unroll
            for (int i = 0; i < 8; ++i){
                long long k = k0 + i;
                float v;
                if      (n <  512) v = load_in(Wr, k*1536 + n, fWr);
                else if (n < 1024) v = load_in(Wl, k*1536 + (n-512), fWl);
                else if (n < 1536) { int c = n-1024; v = load_in(W0, k*512+c, fW0) + load_in(W1, k*512+c, fW1); }
                else               { int c = n-1536; v = load_in(W2, k*512+c, fW2) + load_in(W3, k*512+c, fW3); }
                tmp[i] = f2b(v);
            }
            *(v8s*)&WcatT[(size_t)n*KD + k0] = *(v8s*)tmp;
        }
    }
    {   // bcat
        int fbr=flags[3], fbl=flags[5], fb0=flags[8], fb1=flags[10], fb2=flags[12], fb3=flags[14];
        for (int n = gt; n < 2048; n += GS2){
            float v;
            if      (n <  512) v = load_in(br, n, fbr);
            else if (n < 1024) v = load_in(bl, n-512, fbl);
            else if (n < 1536) v = load_in(b0, n-1024, fb0) + load_in(b1, n-1024, fb1);
            else               v = load_in(b2, n-1536, fb2) + load_in(b3, n-1536, fb3);
            bcat[n] = v;
        }
    }
    {   // xb: 1024 rows x 64 groups
        int f_emb = flags[0], i64i = flags[16];
        for (int u = gt; u < 65536; u += GS2){
            int r = u >> 6, c0 = (u & 63)*8;
            long long base = (long long)idx_read(ids, r, i64i)*E_ + c0;
            unsigned short tmp[8];
            #pragma unroll
            for (int i = 0; i < 8; ++i) tmp[i] = f2b(load_in(emb, base + i, f_emb));
            *(v8s*)&xb[(size_t)r*KD + c0] = *(v8s*)tmp;
        }
    }
    for (int u = gt; u < 262144; u += GS2)   // zero h0+c0 (contiguous 4 MB)
        ((float4*)h0)[u] = make_float4(0.f,0.f,0.f,0.f);
}

// ---- K3: CSR scans ----
__global__ void csr_scan(const int* __restrict__ cnt, int* __restrict__ off,
                         int* __restrict__ cur){
    int st = blockIdx.x, a = blockIdx.y;
    int t = threadIdx.x;   // 1024
    int base = (a*NST + st)*R_;
    __shared__ int sh[R_];
    int v = cnt[base + t];
    sh[t] = v;
    __syncthreads();
    for (int d = 1; d < R_; d <<= 1){
        int x = (t >= d) ? sh[t - d] : 0;
        __syncthreads();
        sh[t] += x;
        __syncthreads();
    }
    int excl = sh[t] - v;
    off[base + t] = excl;
    cur[base + t] = excl;
}

// ---- K4: CSR fill ----
__global__ __launch_bounds__(512)
void csr_fill(const int* __restrict__ tree, int* __restrict__ cur,
              int* __restrict__ ent, const int* __restrict__ flags){
    int is64 = flags[17];
    int st = blockIdx.x;
    for (int ch = 0; ch < 2; ++ch){
        int t = ch*512 + threadIdx.x;
        int b = t >> 7, s = t & 127;
        int base = (b*NST + st)*3*S_;
        int rd = (b<<7) + idx_read(tree, base + s, is64);
        int rr = (b<<7) + idx_read(tree, base + S_ + s, is64);
        int rl = (b<<7) + idx_read(tree, base + 2*S_ + s, is64);
        int p0 = atomicAdd(&cur[(0*NST + st)*R_ + rr], 1);
        ent[(0*NST + st)*R_ + p0] = t;
        int p1 = atomicAdd(&cur[(1*NST + st)*R_ + rl], 1);
        ent[(1*NST + st)*R_ + p1] = t;
        int p2 = atomicAdd(&cur[(2*NST + st)*R_ + rd], 1);
        ent[(2*NST + st)*R_ + p2] = t | (rr << 10) | (rl << 20);
    }
}

// ---- GEMM phase (8-wave K-split): C[1024][2048] = A@BT^T (+bias) ----
// 512 threads: wave-group 0 (waves 0-3) does k[0,256), group 1 does k[256,512);
// each group is the proven 2x2-wave 32x32-quadrant layout over the 64x64 tile.
// Partial accs combined through a 16KB LDS reduction (overlays group-0 LDS).
// A read MALL-coherent (cross-phase); B cached (immutable); C stored MALL.
__device__ __forceinline__ void gemm_phase(const unsigned short* __restrict__ A,
               const unsigned short* __restrict__ BT,
               const float* __restrict__ bias,
               float* __restrict__ C,
               short* __restrict__ SMEM)
{
    int bid = blockIdx.x;
    int bn = (bid & 7)*4 + ((bid >> 3) & 3);   // 0..31, XCD-grouped panels
    int bm = bid >> 5;                          // 0..15
    int tid = threadIdx.x;                      // 0..511
    int lane = tid & 63, wave = tid >> 6;
    int grp = wave >> 2, w4 = wave & 3;
    int wm = w4 & 1, wn = w4 >> 1;
    int lm = lane & 15, quad = lane >> 4;
    short* As = SMEM + grp*(2*64*LDA);
    short* Bs = As + 64*LDA;
    v4f acc[2][2];
    #pragma unroll
    for (int i=0;i<2;++i)
        #pragma unroll
        for (int j=0;j<2;++j) acc[i][j] = (v4f)0.0f;

    int t = tid & 255;
    int srow = t >> 3, sg = (t & 7)*8;
    int kb = grp*256;
    const unsigned short* Ab = A  + (size_t)(bm*64)*KD + kb;
    const unsigned short* Bb = BT + (size_t)(bn*64)*KD + kb;
    v8s pa[2], pb[2];
    #pragma unroll
    for (int j=0;j<2;++j){
        pa[j] = vload16(Ab + (size_t)(j*32+srow)*KD + sg);
        pb[j] = *(const v8s*)(Bb + (size_t)(j*32+srow)*KD + sg);
    }
    for (int k0 = 0; k0 < 256; k0 += 64){
        #pragma unroll
        for (int j=0;j<2;++j){
            *(v8s*)&As[(j*32+srow)*LDA + sg] = pa[j];
            *(v8s*)&Bs[(j*32+srow)*LDA + sg] = pb[j];
        }
        __syncthreads();
        int k1 = k0 + 64;
        if (k1 < 256){
            #pragma unroll
            for (int j=0;j<2;++j){
                pa[j] = vload16(Ab + (size_t)(j*32+srow)*KD + k1 + sg);
                pb[j] = *(const v8s*)(Bb + (size_t)(j*32+srow)*KD + k1 + sg);
            }
        }
        #pragma unroll
        for (int kk = 0; kk < 64; kk += 32){
            v8s af[2], bf[2];
            #pragma unroll
            for (int i=0;i<2;++i){
                af[i] = *(const v8s*)&As[(wm*32 + i*16 + lm)*LDA + kk + quad*8];
                bf[i] = *(const v8s*)&Bs[(wn*32 + i*16 + lm)*LDA + kk + quad*8];
            }
            #pragma unroll
            for (int i=0;i<2;++i)
                #pragma unroll
                for (int j=0;j<2;++j)
                    acc[i][j] = __builtin_amdgcn_mfma_f32_16x16x32_bf16(af[i], bf[j], acc[i][j], 0, 0, 0);
        }
        __syncthreads();
    }
    // combine group-1 partials into group-0 accs via LDS (overlays group-0 As/Bs)
    float* Red = (float*)SMEM;
    if (grp){
        #pragma unroll
        for (int i=0;i<2;++i)
            #pragma unroll
            for (int j=0;j<2;++j)
                #pragma unroll
                for (int rg=0;rg<4;++rg)
                    Red[(wm*32 + i*16 + quad*4 + rg)*64 + (wn*32 + j*16 + lm)] = acc[i][j][rg];
    }
    __syncthreads();
    if (!grp){
        #pragma unroll
        for (int j=0;j<2;++j){
            int n = bn*64 + wn*32 + j*16 + lm;
            float bv = bias ? bias[n] : 0.0f;
            #pragma unroll
            for (int i=0;i<2;++i){
                int m0 = bm*64 + wm*32 + i*16 + quad*4;
                #pragma unroll
                for (int rg = 0; rg < 4; ++rg){
                    float v = acc[i][j][rg] + Red[(wm*32 + i*16 + quad*4 + rg)*64 + (wn*32 + j*16 + lm)] + bv;
                    vstore1(&C[(size_t)(m0+rg)*N2 + n], v);
                }
            }
        }
    }
}

// ---- epi phase: CSR-gathered scatters + gates + masked-scatter ----
// 512 blocks x 512 threads: 2 rows/block, 1 col/thread. All cross-phase data
// via 4B MALL ops; scatter loops unrolled (x4 / x2) to batch MALL latency.
// hb bf16 written as lane-paired 4B stores (msk is block-uniform -> no
// divergent shuffle). tstr=0 with T=bcat implements the step-0 shortcut.
__device__ __forceinline__ void epi_phase(const float* __restrict__ XO,
              const float* __restrict__ T, int tstr,
              const float* __restrict__ hc, const float* __restrict__ cc,
              float* __restrict__ hn, float* __restrict__ cn,
              unsigned short* __restrict__ hb, float* __restrict__ out,
              const int* __restrict__ msk, const int* __restrict__ rnk,
              const int* __restrict__ cnt, const int* __restrict__ off,
              const int* __restrict__ ent, int st, int last)
{
    int c = threadIdx.x;     // 0..511
    #pragma unroll
    for (int rr2 = 0; rr2 < 2; ++rr2){
        int r = blockIdx.x*2 + rr2;
        if (!msk[st*R_ + r]){
            float hv = vload1f(&hc[(size_t)r*H_ + c]);
            if (last){
                out[(size_t)r*H_ + c] = hv;
            } else {
                vstore1(&hn[(size_t)r*H_ + c], hv);
                vstore1(&cn[(size_t)r*H_ + c], vload1f(&cc[(size_t)r*H_ + c]));
                unsigned v16 = f2b(hv);
                unsigned o16 = __shfl_down((int)v16, 1);
                if (!(c & 1)) vstore_hb2(&hb[(size_t)r*KD + c], (unsigned short)v16, (unsigned short)o16);
            }
            continue;
        }
        int j = rnk[st*R_ + r];
        int bR = off[(0*NST+st)*R_ + j], dR = cnt[(0*NST+st)*R_ + j];
        int bL = off[(1*NST+st)*R_ + j], dL = cnt[(1*NST+st)*R_ + j];
        int bD = off[(2*NST+st)*R_ + j], dD = cnt[(2*NST+st)*R_ + j];
        const int* eR = ent + (0*NST+st)*R_ + bR;
        const int* eL = ent + (1*NST+st)*R_ + bL;
        const int* eD = ent + (2*NST+st)*R_ + bD;
        const float* xo = XO + (size_t)j*N2;
        float scv = 0.f;
        {
            int e = 0;
            for (; e + 4 <= dR; e += 4){
                int a0=eR[e], a1=eR[e+1], a2=eR[e+2], a3=eR[e+3];
                float t0 = vload1f(&T[(size_t)a0*tstr + c]);
                float t1 = vload1f(&T[(size_t)a1*tstr + c]);
                float t2 = vload1f(&T[(size_t)a2*tstr + c]);
                float t3 = vload1f(&T[(size_t)a3*tstr + c]);
                scv += (t0 + t1) + (t2 + t3);
            }
            for (; e < dR; ++e) scv += vload1f(&T[(size_t)eR[e]*tstr + c]);
        }
        {
            int e = 0;
            for (; e + 4 <= dL; e += 4){
                int a0=eL[e], a1=eL[e+1], a2=eL[e+2], a3=eL[e+3];
                float t0 = vload1f(&T[(size_t)a0*tstr + 512 + c]);
                float t1 = vload1f(&T[(size_t)a1*tstr + 512 + c]);
                float t2 = vload1f(&T[(size_t)a2*tstr + 512 + c]);
                float t3 = vload1f(&T[(size_t)a3*tstr + 512 + c]);
                scv += (t0 + t1) + (t2 + t3);
            }
            for (; e < dL; ++e) scv += vload1f(&T[(size_t)eL[e]*tstr + 512 + c]);
        }
        float fxv = vload1f(&xo[1536 + c]);
        float csc = 0.f;
        {
            int e = 0;
            for (; e + 2 <= dD; e += 2){
                int p0 = eD[e], p1 = eD[e+1];
                int s0 = p0 & 1023, ra0 = (p0 >> 10) & 1023, rb0 = (p0 >> 20) & 1023;
                int s1 = p1 & 1023, ra1 = (p1 >> 10) & 1023, rb1 = (p1 >> 20) & 1023;
                float ta0 = vload1f(&T[(size_t)ra0*tstr + 1024 + c]);
                float tb0 = vload1f(&T[(size_t)rb0*tstr + 1536 + c]);
                float cv0 = vload1f(&cc[(size_t)s0*H_ + c]);
                float ta1 = vload1f(&T[(size_t)ra1*tstr + 1024 + c]);
                float tb1 = vload1f(&T[(size_t)rb1*tstr + 1536 + c]);
                float cv1 = vload1f(&cc[(size_t)s1*H_ + c]);
                csc += sigm(fxv + ta0 + tb0) * cv0 + sigm(fxv + ta1 + tb1) * cv1;
            }
            for (; e < dD; ++e){
                int pk = eD[e];
                int s  = pk & 1023, ra = (pk >> 10) & 1023, rb = (pk >> 20) & 1023;
                float ta = vload1f(&T[(size_t)ra*tstr + 1024 + c]);
                float tb = vload1f(&T[(size_t)rb*tstr + 1536 + c]);
                float cv = vload1f(&cc[(size_t)s*H_ + c]);
                csc += sigm(fxv + ta + tb) * cv;
            }
        }
        float ig = sigm(vload1f(&xo[c]) + scv);
        float og = sigm(vload1f(&xo[512 + c]));
        float ug = tanhf(vload1f(&xo[1024 + c]));
        float cf = ig*ug + csc;
        float hf = og * tanhf(cf);
        if (last){
            out[(size_t)r*H_ + c] = hf;
        } else {
            vstore1(&hn[(size_t)r*H_ + c], hf);
            vstore1(&cn[(size_t)r*H_ + c], cf);
            unsigned v16 = f2b(hf);
            unsigned o16 = __shfl_down((int)v16, 1);
            if (!(c & 1)) vstore_hb2(&hb[(size_t)r*KD + c], (unsigned short)v16, (unsigned short)o16);
        }
    }
}

// ---- fused chain: XO GEMM + epi0 + 7x(GEMM, epi); counter-only grid barriers ----
// __launch_bounds__(512,4): 4 waves/EU min => VGPR<=128 => 2 blocks/CU
// co-residency is compiler-enforced (gsync deadlock-free by construction).
__global__ __launch_bounds__(512, 4)
void chain_all(const unsigned short* __restrict__ xb,
               const unsigned short* __restrict__ WxT,
               const unsigned short* __restrict__ WcatT,
               const float* __restrict__ bcat,
               float* __restrict__ XO, float* __restrict__ T,
               float* __restrict__ h0, float* __restrict__ c0,
               float* __restrict__ h1, float* __restrict__ c1,
               unsigned short* __restrict__ hb, float* __restrict__ out,
               const int* __restrict__ msk, const int* __restrict__ rnk,
               const int* __restrict__ cnt, const int* __restrict__ off,
               const int* __restrict__ ent, int* bar)
{
    __shared__ short SMEM[4*64*LDA];   // 2 groups x (As+Bs); also the 16KB Red
    int gen = 0;

    // phase 0: XO = xb @ WxT^T (no bias)
    gemm_phase(xb, WxT, (const float*)nullptr, XO, SMEM);
    gsync(bar, ++gen);
    // step 0: h==0 -> T is the bias broadcast; no GEMM needed (tstr=0, T=bcat)
    epi_phase(XO, bcat, 0, h0, c0, h1, c1, hb, out, msk, rnk, cnt, off, ent, 0, 0);
    gsync(bar, ++gen);

    for (int st = 1; st < NST; ++st){
        const float* hcp = (st & 1) ? h1 : h0;
        const float* ccp = (st & 1) ? c1 : c0;
        float* hnp = (st & 1) ? h0 : h1;
        float* cnp = (st & 1) ? c0 : c1;
        gemm_phase(hb, WcatT, bcat, T, SMEM);
        gsync(bar, ++gen);
        epi_phase(XO, T, N2, hcp, ccp, hnp, cnp, hb, out,
                  msk, rnk, cnt, off, ent, st, (st == NST-1) ? 1 : 0);
        if (st < NST-1) gsync(bar, ++gen);
    }
}

extern "C" void kernel_launch(void* const* d_in, const int* in_sizes, int n_in,
                              void* d_out, int out_size, void* d_ws, size_t ws_size,
                              hipStream_t stream) {
    const int* input_ids = (const int*)d_in[0];
    const int* tree      = (const int*)d_in[1];

    char* wp = (char*)d_ws;
    auto alloc = [&](size_t bytes) -> void* {
        void* q = (void*)wp;
        wp += (bytes + 255) & ~(size_t)255;
        return q;
    };
    float*          XO     = (float*)alloc((size_t)R_*N2*4);
    float*          T      = (float*)alloc((size_t)R_*N2*4);
    float*          h0     = (float*)alloc((size_t)R_*H_*4);   // contiguous with c0
    float*          c0     = (float*)alloc((size_t)R_*H_*4);
    float*          h1     = (float*)alloc((size_t)R_*H_*4);
    float*          c1     = (float*)alloc((size_t)R_*H_*4);
    unsigned short* WxT    = (unsigned short*)alloc((size_t)N2*KD*2);
    unsigned short* WcatT  = (unsigned short*)alloc((size_t)N2*KD*2);
    float*          bcat   = (float*)alloc((size_t)N2*4);
    unsigned short* xb     = (unsigned short*)alloc((size_t)R_*KD*2);
    unsigned short* hb     = (unsigned short*)alloc((size_t)R_*KD*2);
    int*            msk    = (int*)alloc((size_t)NST*R_*4);
    int*            rnk    = (int*)alloc((size_t)NST*R_*4);
    int*            cnt    = (int*)alloc((size_t)3*NST*R_*4);
    int*            off    = (int*)alloc((size_t)3*NST*R_*4);
    int*            cur    = (int*)alloc((size_t)3*NST*R_*4);
    int*            ent    = (int*)alloc((size_t)3*NST*R_*4);
    int*            flags  = (int*)alloc(256);
    int*            bar    = (int*)alloc(8192);
    float*          out    = (float*)d_out;   // fp32 output (verified r4)

    hipLaunchKernelGGL(probe_all, dim3(17), dim3(1024), 0, stream,
                       d_in[2], d_in[3], d_in[4], d_in[5], d_in[6], d_in[7], d_in[8],
                       d_in[9], d_in[10], d_in[11], d_in[12], d_in[13], d_in[14],
                       d_in[15], d_in[16], input_ids, tree, flags);
    hipLaunchKernelGGL(rank_pack, dim3(NB2), dim3(512), 0, stream,
                       d_in[3], d_in[8],
                       d_in[4], d_in[6], d_in[9], d_in[11], d_in[13], d_in[15],
                       d_in[5], d_in[7], d_in[10], d_in[12], d_in[14], d_in[16],
                       input_ids, d_in[2], tree,
                       WxT, WcatT, bcat, xb, h0, msk, rnk, cnt, flags, bar);
    hipLaunchKernelGGL(csr_scan, dim3(NST, 3), dim3(1024), 0, stream, cnt, off, cur);
    hipLaunchKernelGGL(csr_fill, dim3(NST), dim3(512), 0, stream, tree, cur, ent, flags);

    // single fused kernel for the whole step chain (512 blocks x 512 thr, 2/CU resident)
    hipLaunchKernelGGL(chain_all, dim3(NBLK), dim3(512), 0, stream,
                       xb, WxT, WcatT, bcat, XO, T, h0, c0, h1, c1, hb, out,
                       msk, rnk, cnt, off, ent, bar);
}